// Round 1
// baseline (547.216 us; speedup 1.0000x reference)
//
#include <hip/hip_runtime.h>
#include <math.h>

// ---------------------------------------------------------------------------
// Live computation (dead-code-eliminated reference):
//   dinv[v]   = rsqrt(indeg(v)+1)
//   aggx      = A_norm @ x                    (A includes self loops)
//   h1s       = relu(aggx @ c1W + c1b) * dinv  (pre-scaled for next gather)
//   aggh1     = A_norm @ h1   (== dinv[v]*(sum_in h1s[s] + h1s[v]))
//   h2        = relu([aggh1, aggx] @ c2W + c2b)
//   h4        = relu([x, h2] @ f4W + f4b)
//   out       = sigmoid([x, h4] @ f5W + f5b)
// ---------------------------------------------------------------------------

__global__ __launch_bounds__(256) void hist_kernel(const int* __restrict__ ei,
                                                   int* __restrict__ cnt, int E, int N) {
    int e = blockIdx.x * 256 + threadIdx.x;
    if (e < E) {
        unsigned d = (unsigned)ei[2 * e + 1];
        if (d < (unsigned)N) atomicAdd(&cnt[d], 1);
    }
}

__global__ __launch_bounds__(256) void dinv_xs_kernel(const int* __restrict__ cnt,
                                                      const float* __restrict__ x,
                                                      float* __restrict__ dinv,
                                                      float* __restrict__ xs, int n) {
    int v = blockIdx.x * 256 + threadIdx.x;
    if (v >= n) return;
    float dv = rsqrtf((float)(cnt[v] + 1));
    dinv[v] = dv;
    const float4* x4 = (const float4*)x;
    float4 a = x4[v * 2], b = x4[v * 2 + 1];
    float4* o = (float4*)xs;
    o[v * 2]     = make_float4(a.x * dv, a.y * dv, a.z * dv, a.w * dv);
    o[v * 2 + 1] = make_float4(b.x * dv, b.y * dv, b.z * dv, b.w * dv);
}

// exclusive scan of cnt[0..N-1] (index >= N treated as 0) into rowptr[0..ntot-1]
__global__ __launch_bounds__(1024) void scan1_kernel(const int* __restrict__ cnt,
                                                     int* __restrict__ rowptr,
                                                     int* __restrict__ bsum, int ntot, int N) {
    __shared__ int lds[1024];
    int i = blockIdx.x * 1024 + threadIdx.x;
    int v = (i < N) ? cnt[i] : 0;
    lds[threadIdx.x] = v;
    __syncthreads();
    for (int off = 1; off < 1024; off <<= 1) {
        int y = (threadIdx.x >= off) ? lds[threadIdx.x - off] : 0;
        __syncthreads();
        if (threadIdx.x >= off) lds[threadIdx.x] += y;
        __syncthreads();
    }
    if (i < ntot) rowptr[i] = lds[threadIdx.x] - v;           // exclusive
    if (threadIdx.x == 1023) bsum[blockIdx.x] = lds[1023];    // block total
}

__global__ __launch_bounds__(1024) void scan2_kernel(int* __restrict__ bsum, int B) {
    __shared__ int lds[1024];
    int v = (threadIdx.x < B) ? bsum[threadIdx.x] : 0;
    lds[threadIdx.x] = v;
    __syncthreads();
    for (int off = 1; off < 1024; off <<= 1) {
        int y = (threadIdx.x >= off) ? lds[threadIdx.x - off] : 0;
        __syncthreads();
        if (threadIdx.x >= off) lds[threadIdx.x] += y;
        __syncthreads();
    }
    if (threadIdx.x < B) bsum[threadIdx.x] = lds[threadIdx.x] - v;  // exclusive
}

__global__ __launch_bounds__(256) void scan3_kernel(int* __restrict__ rowptr,
                                                    const int* __restrict__ bsum, int ntot) {
    int i = blockIdx.x * 256 + threadIdx.x;
    if (i < ntot) rowptr[i] += bsum[i >> 10];
}

__global__ __launch_bounds__(256) void fill_kernel(const int* __restrict__ ei,
                                                   int* __restrict__ cursor,
                                                   int* __restrict__ col, int E, int N) {
    int e = blockIdx.x * 256 + threadIdx.x;
    if (e < E) {
        unsigned s = (unsigned)ei[2 * e];
        unsigned d = (unsigned)ei[2 * e + 1];
        if (d < (unsigned)N) {
            int pos = atomicAdd(&cursor[d], 1);
            col[pos] = (s < (unsigned)N) ? (int)s : 0;
        }
    }
}

// agg over 8 features, thread per node (xs is L2-resident: 3.2 MB)
__global__ __launch_bounds__(256) void agg8_kernel(const float* __restrict__ xs,
                                                   const int* __restrict__ rowptr,
                                                   const int* __restrict__ col,
                                                   const float* __restrict__ dinv,
                                                   float* __restrict__ aggx, int n) {
    int v = blockIdx.x * 256 + threadIdx.x;
    if (v >= n) return;
    const float4* r4 = (const float4*)xs;
    float4 a = make_float4(0, 0, 0, 0), b = make_float4(0, 0, 0, 0);
    int end = rowptr[v + 1];
    for (int j = rowptr[v]; j < end; j++) {
        int s = col[j];
        float4 p = r4[(size_t)s * 2], q = r4[(size_t)s * 2 + 1];
        a.x += p.x; a.y += p.y; a.z += p.z; a.w += p.w;
        b.x += q.x; b.y += q.y; b.z += q.z; b.w += q.w;
    }
    float4 p = r4[(size_t)v * 2], q = r4[(size_t)v * 2 + 1];
    a.x += p.x; a.y += p.y; a.z += p.z; a.w += p.w;
    b.x += q.x; b.y += q.y; b.z += q.z; b.w += q.w;
    float dv = dinv[v];
    float4* o = (float4*)aggx;
    o[(size_t)v * 2]     = make_float4(a.x * dv, a.y * dv, a.z * dv, a.w * dv);
    o[(size_t)v * 2 + 1] = make_float4(b.x * dv, b.y * dv, b.z * dv, b.w * dv);
}

// agg over 128 features: one wave per node, lane holds float2 (2 features)
__global__ __launch_bounds__(256) void agg128_kernel(const float* __restrict__ h1s,
                                                     const int* __restrict__ rowptr,
                                                     const int* __restrict__ col,
                                                     const float* __restrict__ dinv,
                                                     float* __restrict__ out, int n) {
    int v = blockIdx.x * 4 + (threadIdx.x >> 6);
    int lane = threadIdx.x & 63;
    if (v >= n) return;
    const float2* rows = (const float2*)h1s;
    float2 acc = make_float2(0.f, 0.f);
    int start = rowptr[v], end = rowptr[v + 1];
    for (int base = start; base < end; base += 64) {
        int m = end - base; if (m > 64) m = 64;
        int si = (lane < m) ? col[base + lane] : 0;
        int t = 0;
        for (; t + 4 <= m; t += 4) {
            int s0 = __shfl(si, t),     s1 = __shfl(si, t + 1);
            int s2 = __shfl(si, t + 2), s3 = __shfl(si, t + 3);
            float2 a0 = rows[(size_t)s0 * 64 + lane];
            float2 a1 = rows[(size_t)s1 * 64 + lane];
            float2 a2 = rows[(size_t)s2 * 64 + lane];
            float2 a3 = rows[(size_t)s3 * 64 + lane];
            acc.x += (a0.x + a1.x) + (a2.x + a3.x);
            acc.y += (a0.y + a1.y) + (a2.y + a3.y);
        }
        for (; t < m; t++) {
            int s = __shfl(si, t);
            float2 a = rows[(size_t)s * 64 + lane];
            acc.x += a.x; acc.y += a.y;
        }
    }
    float2 self = rows[(size_t)v * 64 + lane];
    acc.x += self.x; acc.y += self.y;
    float dv = dinv[v];
    ((float2*)out)[(size_t)v * 64 + lane] = make_float2(acc.x * dv, acc.y * dv);
}

// Generic dense layer: out128 = act([A1(K1) | A2(K2)] @ W + b)
// MODE 0: relu, then scale by dinv (produces pre-scaled h1s)
// MODE 1: relu
// MODE 2: relu -> h4, then fused f5: out[node] = sigmoid([A1row, h4] @ f5W + f5b)
template <int K1, int K2, int MODE>
__global__ __launch_bounds__(256) void gemm_kernel(
    const float* __restrict__ A1, const float* __restrict__ A2,
    const float* __restrict__ W, const float* __restrict__ bias,
    const float* __restrict__ dinv,
    const float* __restrict__ f5W, const float* __restrict__ f5b,
    float* __restrict__ out, int n) {
    constexpr int K = K1 + K2;
    constexpr int NPB = 16;
    __shared__ float lds[NPB * K];
    __shared__ float xdot[NPB];

    int node0 = blockIdx.x * NPB;

    // stage NPB rows of [A1|A2] into LDS (coalesced)
    for (int idx = threadIdx.x; idx < NPB * K; idx += 256) {
        int r = idx / K, k = idx - r * K;
        int node = node0 + r;
        float v = 0.f;
        if (node < n)
            v = (k < K1) ? A1[(size_t)node * K1 + k] : A2[(size_t)node * K2 + (k - K1)];
        lds[idx] = v;
    }
    __syncthreads();

    int f = threadIdx.x & 127;
    int g = threadIdx.x >> 7;   // 0/1: which half of the node pairs
    float acc[8];
#pragma unroll
    for (int i = 0; i < 8; i++) acc[i] = 0.f;

    for (int k = 0; k < K; k += 4) {
        float w0 = W[(size_t)(k + 0) * 128 + f];
        float w1 = W[(size_t)(k + 1) * 128 + f];
        float w2 = W[(size_t)(k + 2) * 128 + f];
        float w3 = W[(size_t)(k + 3) * 128 + f];
#pragma unroll
        for (int i = 0; i < 8; i++) {
            float4 a = *(const float4*)&lds[(2 * i + g) * K + k];  // wave-broadcast
            acc[i] += a.x * w0 + a.y * w1 + a.z * w2 + a.w * w3;
        }
    }

    float b = bias[f];

    if (MODE == 0) {
#pragma unroll
        for (int i = 0; i < 8; i++) {
            int node = node0 + 2 * i + g;
            if (node < n)
                out[(size_t)node * 128 + f] = fmaxf(acc[i] + b, 0.f) * dinv[node];
        }
    } else if (MODE == 1) {
#pragma unroll
        for (int i = 0; i < 8; i++) {
            int node = node0 + 2 * i + g;
            if (node < n)
                out[(size_t)node * 128 + f] = fmaxf(acc[i] + b, 0.f);
        }
    } else {
        // MODE 2: fused f5 epilogue
        float h4v[8];
#pragma unroll
        for (int i = 0; i < 8; i++) h4v[i] = fmaxf(acc[i] + b, 0.f);
        __syncthreads();
        // per-node dot of the x-part (first K1 lds cols) with f5W[0..K1)
        if (threadIdx.x < NPB) {
            float s = 0.f;
#pragma unroll
            for (int k = 0; k < K1; k++) s += lds[threadIdx.x * K + k] * f5W[k];
            xdot[threadIdx.x] = s;
        }
        __syncthreads();
#pragma unroll
        for (int i = 0; i < 8; i++) lds[(2 * i + g) * 128 + f] = h4v[i];
        __syncthreads();
        int lane = threadIdx.x & 63;
        int wv = threadIdx.x >> 6;
        float fb = f5b[0];
        for (int jj = 0; jj < NPB / 4; jj++) {
            int j = wv * (NPB / 4) + jj;
            int node = node0 + j;
            float p = lds[j * 128 + lane] * f5W[K1 + lane]
                    + lds[j * 128 + 64 + lane] * f5W[K1 + 64 + lane];
#pragma unroll
            for (int o = 32; o > 0; o >>= 1) p += __shfl_xor(p, o);
            if (lane == 0 && node < n)
                out[node] = 1.f / (1.f + expf(-(p + xdot[j] + fb)));
        }
    }
}

extern "C" void kernel_launch(void* const* d_in, const int* in_sizes, int n_in,
                              void* d_out, int out_size, void* d_ws, size_t ws_size,
                              hipStream_t stream) {
    const float* x   = (const float*)d_in[0];
    const int*   ei  = (const int*)d_in[1];
    const float* c1W = (const float*)d_in[2];
    const float* c1b = (const float*)d_in[3];
    const float* c2W = (const float*)d_in[4];
    const float* c2b = (const float*)d_in[5];
    const float* f4W = (const float*)d_in[18];
    const float* f4b = (const float*)d_in[19];
    const float* f5W = (const float*)d_in[20];
    const float* f5b = (const float*)d_in[21];
    float* out = (float*)d_out;

    int N = in_sizes[0] / 8;
    int E = in_sizes[1] / 2;

    char* p = (char*)d_ws;
    auto alloc = [&](size_t bytes) {
        char* q = p;
        p += (bytes + 255) & ~(size_t)255;
        return q;
    };
    int*   cnt    = (int*)alloc((size_t)N * 4);
    int*   rowptr = (int*)alloc((size_t)(N + 1) * 4);
    int*   cursor = (int*)alloc((size_t)N * 4);
    int*   bsum   = (int*)alloc(4096);
    float* dinv   = (float*)alloc((size_t)N * 4);
    int*   col    = (int*)alloc((size_t)E * 4);
    float* xs     = (float*)alloc((size_t)N * 8 * 4);
    float* aggx   = (float*)alloc((size_t)N * 8 * 4);
    float* bufA   = (float*)alloc((size_t)N * 128 * 4);  // h1s, then h2
    float* bufB   = (float*)alloc((size_t)N * 128 * 4);  // agg_h1

    hipMemsetAsync(cnt, 0, (size_t)N * 4, stream);

    int gE = (E + 255) / 256;
    int gN = (N + 255) / 256;
    hist_kernel<<<gE, 256, 0, stream>>>(ei, cnt, E, N);
    dinv_xs_kernel<<<gN, 256, 0, stream>>>(cnt, x, dinv, xs, N);

    int ntot = N + 1;
    int B = (ntot + 1023) / 1024;
    scan1_kernel<<<B, 1024, 0, stream>>>(cnt, rowptr, bsum, ntot, N);
    scan2_kernel<<<1, 1024, 0, stream>>>(bsum, B);
    scan3_kernel<<<(ntot + 255) / 256, 256, 0, stream>>>(rowptr, bsum, ntot);

    hipMemcpyAsync(cursor, rowptr, (size_t)N * 4, hipMemcpyDeviceToDevice, stream);
    fill_kernel<<<gE, 256, 0, stream>>>(ei, cursor, col, E, N);

    agg8_kernel<<<gN, 256, 0, stream>>>(xs, rowptr, col, dinv, aggx, N);

    int gG = (N + 15) / 16;
    // h1s = relu(aggx @ c1W + c1b) * dinv
    gemm_kernel<8, 0, 0><<<gG, 256, 0, stream>>>(aggx, nullptr, c1W, c1b, dinv,
                                                 nullptr, nullptr, bufA, N);
    // aggh1 = A_norm @ h1
    agg128_kernel<<<(N + 3) / 4, 256, 0, stream>>>(bufA, rowptr, col, dinv, bufB, N);
    // h2 = relu([aggh1, aggx] @ c2W + c2b)   (into bufA; h1s now dead)
    gemm_kernel<128, 8, 1><<<gG, 256, 0, stream>>>(bufB, aggx, c2W, c2b, nullptr,
                                                   nullptr, nullptr, bufA, N);
    // h4 = relu([x, h2] @ f4W + f4b); out = sigmoid([x, h4] @ f5W + f5b)
    gemm_kernel<8, 128, 2><<<gG, 256, 0, stream>>>(x, bufA, f4W, f4b, nullptr,
                                                   f5W, f5b, out, N);
}

// Round 2
// 445.905 us; speedup vs baseline: 1.2272x; 1.2272x over previous
//
#include <hip/hip_runtime.h>
#include <hip/hip_bf16.h>
#include <math.h>

// ---------------------------------------------------------------------------
// Live computation (dead-code-eliminated reference):
//   dinv[v]   = rsqrt(indeg(v)+1)
//   aggx      = A_norm @ x                    (A includes self loops)
//   h1s       = relu(aggx @ c1W + c1b) * dinv  (pre-scaled, stored BF16)
//   aggh1     = A_norm @ h1   (== dinv[v]*(sum_in h1s[s] + h1s[v]))
//   h2        = relu([aggh1, aggx] @ c2W + c2b)
//   h4        = relu([x, h2] @ f4W + f4b)
//   out       = sigmoid([x, h4] @ f5W + f5b)
// ---------------------------------------------------------------------------

__global__ __launch_bounds__(256) void hist_kernel(const int* __restrict__ ei,
                                                   int* __restrict__ cnt, int E, int N) {
    int e = blockIdx.x * 256 + threadIdx.x;
    if (e < E) {
        unsigned d = (unsigned)ei[2 * e + 1];
        if (d < (unsigned)N) atomicAdd(&cnt[d], 1);
    }
}

__global__ __launch_bounds__(256) void dinv_xs_kernel(const int* __restrict__ cnt,
                                                      const float* __restrict__ x,
                                                      float* __restrict__ dinv,
                                                      float* __restrict__ xs, int n) {
    int v = blockIdx.x * 256 + threadIdx.x;
    if (v >= n) return;
    float dv = rsqrtf((float)(cnt[v] + 1));
    dinv[v] = dv;
    const float4* x4 = (const float4*)x;
    float4 a = x4[v * 2], b = x4[v * 2 + 1];
    float4* o = (float4*)xs;
    o[v * 2]     = make_float4(a.x * dv, a.y * dv, a.z * dv, a.w * dv);
    o[v * 2 + 1] = make_float4(b.x * dv, b.y * dv, b.z * dv, b.w * dv);
}

// exclusive scan of cnt[0..N-1] (index >= N treated as 0) into rowptr[0..ntot-1]
__global__ __launch_bounds__(1024) void scan1_kernel(const int* __restrict__ cnt,
                                                     int* __restrict__ rowptr,
                                                     int* __restrict__ bsum, int ntot, int N) {
    __shared__ int lds[1024];
    int i = blockIdx.x * 1024 + threadIdx.x;
    int v = (i < N) ? cnt[i] : 0;
    lds[threadIdx.x] = v;
    __syncthreads();
    for (int off = 1; off < 1024; off <<= 1) {
        int y = (threadIdx.x >= off) ? lds[threadIdx.x - off] : 0;
        __syncthreads();
        if (threadIdx.x >= off) lds[threadIdx.x] += y;
        __syncthreads();
    }
    if (i < ntot) rowptr[i] = lds[threadIdx.x] - v;           // exclusive
    if (threadIdx.x == 1023) bsum[blockIdx.x] = lds[1023];    // block total
}

__global__ __launch_bounds__(1024) void scan2_kernel(int* __restrict__ bsum, int B) {
    __shared__ int lds[1024];
    int v = (threadIdx.x < B) ? bsum[threadIdx.x] : 0;
    lds[threadIdx.x] = v;
    __syncthreads();
    for (int off = 1; off < 1024; off <<= 1) {
        int y = (threadIdx.x >= off) ? lds[threadIdx.x - off] : 0;
        __syncthreads();
        if (threadIdx.x >= off) lds[threadIdx.x] += y;
        __syncthreads();
    }
    if (threadIdx.x < B) bsum[threadIdx.x] = lds[threadIdx.x] - v;  // exclusive
}

__global__ __launch_bounds__(256) void scan3_kernel(int* __restrict__ rowptr,
                                                    const int* __restrict__ bsum, int ntot) {
    int i = blockIdx.x * 256 + threadIdx.x;
    if (i < ntot) rowptr[i] += bsum[i >> 10];
}

// XCD-partitioned CSR fill: part p (= blockIdx & 7, the default XCD round-robin)
// handles destinations in [N*p/8, N*(p+1)/8). Each XCD's col slice (~0.8 MB)
// stays L2-resident until its 64B lines are fully populated -> writeback once.
__global__ __launch_bounds__(256) void fill_part_kernel(const int* __restrict__ ei,
                                                        int* __restrict__ cursor,
                                                        int* __restrict__ col,
                                                        int E, int N, int nchunk) {
    int part = blockIdx.x & 7;
    int chunk = blockIdx.x >> 3;
    int lo = (int)(((long long)N * part) >> 3);
    int hi = (int)(((long long)N * (part + 1)) >> 3);
    int stride = nchunk * 256;
    for (int e = chunk * 256 + threadIdx.x; e < E; e += stride) {
        int2 pq = ((const int2*)ei)[e];
        int s = pq.x, d = pq.y;
        if (d >= lo && d < hi) {
            int pos = atomicAdd(&cursor[d], 1);
            col[pos] = ((unsigned)s < (unsigned)N) ? s : 0;
        }
    }
}

// agg over 8 features, thread per node (xs is L2-resident: 3.2 MB)
__global__ __launch_bounds__(256) void agg8_kernel(const float* __restrict__ xs,
                                                   const int* __restrict__ rowptr,
                                                   const int* __restrict__ col,
                                                   const float* __restrict__ dinv,
                                                   float* __restrict__ aggx, int n) {
    int v = blockIdx.x * 256 + threadIdx.x;
    if (v >= n) return;
    const float4* r4 = (const float4*)xs;
    float4 a = make_float4(0, 0, 0, 0), b = make_float4(0, 0, 0, 0);
    int end = rowptr[v + 1];
    for (int j = rowptr[v]; j < end; j++) {
        int s = col[j];
        float4 p = r4[(size_t)s * 2], q = r4[(size_t)s * 2 + 1];
        a.x += p.x; a.y += p.y; a.z += p.z; a.w += p.w;
        b.x += q.x; b.y += q.y; b.z += q.z; b.w += q.w;
    }
    float4 p = r4[(size_t)v * 2], q = r4[(size_t)v * 2 + 1];
    a.x += p.x; a.y += p.y; a.z += p.z; a.w += p.w;
    b.x += q.x; b.y += q.y; b.z += q.z; b.w += q.w;
    float dv = dinv[v];
    float4* o = (float4*)aggx;
    o[(size_t)v * 2]     = make_float4(a.x * dv, a.y * dv, a.z * dv, a.w * dv);
    o[(size_t)v * 2 + 1] = make_float4(b.x * dv, b.y * dv, b.z * dv, b.w * dv);
}

// agg over 128 bf16 features: one wave per node, lane holds 2 features (uint)
__global__ __launch_bounds__(256) void agg128_kernel(const unsigned* __restrict__ rows,
                                                     const int* __restrict__ rowptr,
                                                     const int* __restrict__ col,
                                                     const float* __restrict__ dinv,
                                                     float* __restrict__ out, int n) {
    int v = blockIdx.x * 4 + (threadIdx.x >> 6);
    int lane = threadIdx.x & 63;
    if (v >= n) return;
    float ax = 0.f, ay = 0.f;
    int start = rowptr[v], end = rowptr[v + 1];
    for (int base = start; base < end; base += 64) {
        int m = end - base; if (m > 64) m = 64;
        int si = (lane < m) ? col[base + lane] : 0;
        int t = 0;
        for (; t + 4 <= m; t += 4) {
            int s0 = __shfl(si, t),     s1 = __shfl(si, t + 1);
            int s2 = __shfl(si, t + 2), s3 = __shfl(si, t + 3);
            unsigned u0 = rows[(size_t)s0 * 64 + lane];
            unsigned u1 = rows[(size_t)s1 * 64 + lane];
            unsigned u2 = rows[(size_t)s2 * 64 + lane];
            unsigned u3 = rows[(size_t)s3 * 64 + lane];
            ax += (__uint_as_float(u0 << 16) + __uint_as_float(u1 << 16))
                + (__uint_as_float(u2 << 16) + __uint_as_float(u3 << 16));
            ay += (__uint_as_float(u0 & 0xffff0000u) + __uint_as_float(u1 & 0xffff0000u))
                + (__uint_as_float(u2 & 0xffff0000u) + __uint_as_float(u3 & 0xffff0000u));
        }
        for (; t < m; t++) {
            int s = __shfl(si, t);
            unsigned u = rows[(size_t)s * 64 + lane];
            ax += __uint_as_float(u << 16);
            ay += __uint_as_float(u & 0xffff0000u);
        }
    }
    unsigned us = rows[(size_t)v * 64 + lane];
    ax += __uint_as_float(us << 16);
    ay += __uint_as_float(us & 0xffff0000u);
    float dv = dinv[v];
    ((float2*)out)[(size_t)v * 64 + lane] = make_float2(ax * dv, ay * dv);
}

// Generic dense layer: out128 = act([A1(K1) | A2(K2)] @ W + b)
// MODE 0: relu, scale by dinv, store BF16 (pre-scaled h1s for the gather)
// MODE 1: relu, store f32
// MODE 2: relu -> h4, then fused f5: out[node] = sigmoid([A1row, h4] @ f5W + f5b)
template <int K1, int K2, int MODE>
__global__ __launch_bounds__(256) void gemm_kernel(
    const float* __restrict__ A1, const float* __restrict__ A2,
    const float* __restrict__ W, const float* __restrict__ bias,
    const float* __restrict__ dinv,
    const float* __restrict__ f5W, const float* __restrict__ f5b,
    void* __restrict__ outv, int n) {
    constexpr int K = K1 + K2;
    constexpr int NPB = 16;
    __shared__ float lds[NPB * K];
    __shared__ float xdot[NPB];

    int node0 = blockIdx.x * NPB;

    // stage NPB rows of [A1|A2] into LDS (coalesced)
    for (int idx = threadIdx.x; idx < NPB * K; idx += 256) {
        int r = idx / K, k = idx - r * K;
        int node = node0 + r;
        float v = 0.f;
        if (node < n)
            v = (k < K1) ? A1[(size_t)node * K1 + k] : A2[(size_t)node * K2 + (k - K1)];
        lds[idx] = v;
    }
    __syncthreads();

    int f = threadIdx.x & 127;
    int g = threadIdx.x >> 7;   // 0/1: which half of the node pairs
    float acc[8];
#pragma unroll
    for (int i = 0; i < 8; i++) acc[i] = 0.f;

    for (int k = 0; k < K; k += 4) {
        float w0 = W[(size_t)(k + 0) * 128 + f];
        float w1 = W[(size_t)(k + 1) * 128 + f];
        float w2 = W[(size_t)(k + 2) * 128 + f];
        float w3 = W[(size_t)(k + 3) * 128 + f];
#pragma unroll
        for (int i = 0; i < 8; i++) {
            float4 a = *(const float4*)&lds[(2 * i + g) * K + k];  // wave-broadcast
            acc[i] += a.x * w0 + a.y * w1 + a.z * w2 + a.w * w3;
        }
    }

    float b = bias[f];

    if (MODE == 0) {
        __hip_bfloat16* out = (__hip_bfloat16*)outv;
#pragma unroll
        for (int i = 0; i < 8; i++) {
            int node = node0 + 2 * i + g;
            if (node < n)
                out[(size_t)node * 128 + f] =
                    __float2bfloat16(fmaxf(acc[i] + b, 0.f) * dinv[node]);
        }
    } else if (MODE == 1) {
        float* out = (float*)outv;
#pragma unroll
        for (int i = 0; i < 8; i++) {
            int node = node0 + 2 * i + g;
            if (node < n)
                out[(size_t)node * 128 + f] = fmaxf(acc[i] + b, 0.f);
        }
    } else {
        // MODE 2: fused f5 epilogue
        float* out = (float*)outv;
        float h4v[8];
#pragma unroll
        for (int i = 0; i < 8; i++) h4v[i] = fmaxf(acc[i] + b, 0.f);
        __syncthreads();
        // per-node dot of the x-part (first K1 lds cols) with f5W[0..K1)
        if (threadIdx.x < NPB) {
            float s = 0.f;
#pragma unroll
            for (int k = 0; k < K1; k++) s += lds[threadIdx.x * K + k] * f5W[k];
            xdot[threadIdx.x] = s;
        }
        __syncthreads();
#pragma unroll
        for (int i = 0; i < 8; i++) lds[(2 * i + g) * 128 + f] = h4v[i];
        __syncthreads();
        int lane = threadIdx.x & 63;
        int wv = threadIdx.x >> 6;
        float fb = f5b[0];
        for (int jj = 0; jj < NPB / 4; jj++) {
            int j = wv * (NPB / 4) + jj;
            int node = node0 + j;
            float p = lds[j * 128 + lane] * f5W[K1 + lane]
                    + lds[j * 128 + 64 + lane] * f5W[K1 + 64 + lane];
#pragma unroll
            for (int o = 32; o > 0; o >>= 1) p += __shfl_xor(p, o);
            if (lane == 0 && node < n)
                out[node] = 1.f / (1.f + expf(-(p + xdot[j] + fb)));
        }
    }
}

extern "C" void kernel_launch(void* const* d_in, const int* in_sizes, int n_in,
                              void* d_out, int out_size, void* d_ws, size_t ws_size,
                              hipStream_t stream) {
    const float* x   = (const float*)d_in[0];
    const int*   ei  = (const int*)d_in[1];
    const float* c1W = (const float*)d_in[2];
    const float* c1b = (const float*)d_in[3];
    const float* c2W = (const float*)d_in[4];
    const float* c2b = (const float*)d_in[5];
    const float* f4W = (const float*)d_in[18];
    const float* f4b = (const float*)d_in[19];
    const float* f5W = (const float*)d_in[20];
    const float* f5b = (const float*)d_in[21];
    float* out = (float*)d_out;

    int N = in_sizes[0] / 8;
    int E = in_sizes[1] / 2;

    char* p = (char*)d_ws;
    auto alloc = [&](size_t bytes) {
        char* q = p;
        p += (bytes + 255) & ~(size_t)255;
        return q;
    };
    int*   cnt    = (int*)alloc((size_t)N * 4);
    int*   rowptr = (int*)alloc((size_t)(N + 1) * 4);
    int*   cursor = (int*)alloc((size_t)N * 4);
    int*   bsum   = (int*)alloc(4096);
    float* dinv   = (float*)alloc((size_t)N * 4);
    int*   col    = (int*)alloc((size_t)E * 4);
    float* xs     = (float*)alloc((size_t)N * 8 * 4);
    float* aggx   = (float*)alloc((size_t)N * 8 * 4);
    float* bufA   = (float*)alloc((size_t)N * 128 * 4);  // h1s (bf16), then h2 (f32)
    float* bufB   = (float*)alloc((size_t)N * 128 * 4);  // agg_h1 (f32)

    hipMemsetAsync(cnt, 0, (size_t)N * 4, stream);

    int gE = (E + 255) / 256;
    int gN = (N + 255) / 256;
    hist_kernel<<<gE, 256, 0, stream>>>(ei, cnt, E, N);
    dinv_xs_kernel<<<gN, 256, 0, stream>>>(cnt, x, dinv, xs, N);

    int ntot = N + 1;
    int B = (ntot + 1023) / 1024;
    scan1_kernel<<<B, 1024, 0, stream>>>(cnt, rowptr, bsum, ntot, N);
    scan2_kernel<<<1, 1024, 0, stream>>>(bsum, B);
    scan3_kernel<<<(ntot + 255) / 256, 256, 0, stream>>>(rowptr, bsum, ntot);

    hipMemcpyAsync(cursor, rowptr, (size_t)N * 4, hipMemcpyDeviceToDevice, stream);

    // XCD-partitioned fill: 8 parts x nchunk chunks
    int nchunk = 256;
    fill_part_kernel<<<8 * nchunk, 256, 0, stream>>>(ei, cursor, col, E, N, nchunk);

    agg8_kernel<<<gN, 256, 0, stream>>>(xs, rowptr, col, dinv, aggx, N);

    int gG = (N + 15) / 16;
    // h1s = bf16( relu(aggx @ c1W + c1b) * dinv )
    gemm_kernel<8, 0, 0><<<gG, 256, 0, stream>>>(aggx, nullptr, c1W, c1b, dinv,
                                                 nullptr, nullptr, bufA, N);
    // aggh1 = A_norm @ h1  (bf16 gather, f32 accumulate)
    agg128_kernel<<<(N + 3) / 4, 256, 0, stream>>>((const unsigned*)bufA, rowptr, col,
                                                   dinv, bufB, N);
    // h2 = relu([aggh1, aggx] @ c2W + c2b)   (into bufA; h1s now dead)
    gemm_kernel<128, 8, 1><<<gG, 256, 0, stream>>>(bufB, aggx, c2W, c2b, nullptr,
                                                   nullptr, nullptr, bufA, N);
    // h4 = relu([x, h2] @ f4W + f4b); out = sigmoid([x, h4] @ f5W + f5b)
    gemm_kernel<8, 128, 2><<<gG, 256, 0, stream>>>(x, bufA, f4W, f4b, nullptr,
                                                   f5W, f5b, out, N);
}